// Round 4
// baseline (763.195 us; speedup 1.0000x reference)
//
#include <hip/hip_runtime.h>
#include <hip/hip_bf16.h>
#include <stdint.h>

// IDFT as one real GEMM:  C(32768 x 2048) = A(32768 x 2048) * B(2048 x 2048)
//   A = [re | im] along K;  B = [[Mr, Mi], [-Mi, Mr]]
// Round 4 (= round 3 resubmitted after GPU-acquisition timeout):
// 256x256 8-phase schedule (T2 swizzle + T3/T4 counted vmcnt + T5 setprio).
// Per K-tile (BK=64): 4 phases, phase (qm,qn) computes block-level C-quadrant
// [qm*128,+128)x[qn*128,+128) over K=64 -> each phase reads exactly one
// A-half + one B-half of LDS. Stage stream per K-tile t:
//   ph1: B1(t+1)  ph2: A1(t+1)  ph3: A0(t+2)  ph4: B0(t+2) + vmcnt(4)
// Overwrite safety: A0 last read ph2, B0 ph3, B1/A1 ph4 -> every stage lands
// >=1 barrier after the victim's last read. vmcnt(4) at t.4 guarantees tile
// t+1 fully landed (staged through t.2) while keeping 2 half-tiles in flight.

typedef __attribute__((ext_vector_type(4))) float f32x4;
typedef __attribute__((ext_vector_type(8))) short bf16x8;

typedef const __attribute__((address_space(1))) void* gas_ptr;
typedef __attribute__((address_space(3))) void* las_ptr;

static __device__ __forceinline__ short f2bf(float f) {
  __hip_bfloat16 h = __float2bfloat16(f);
  return *reinterpret_cast<short*>(&h);
}

// ---------------------------------------------------------------------------
// Prologue 1: build B^T (2048 x 2048, bf16, row-major [n][k]) into ws.
// ---------------------------------------------------------------------------
__global__ __launch_bounds__(256) void build_bt(const float* __restrict__ fr,
                                                const float* __restrict__ fi,
                                                __hip_bfloat16* __restrict__ bt) {
  __shared__ float tile[64][65];
  const int bid = blockIdx.x;            // 32 x 32 tiles of 64x64
  const int ktile = (bid >> 5) << 6;
  const int ntile = (bid & 31) << 6;
  const bool kq = ktile >= 1024, nq = ntile >= 1024;
  const float* src = (kq == nq) ? fr : fi;
  const float sgn = (kq && !nq) ? -1.f : 1.f;
  const int ks = ktile & 1023, ns = ntile & 1023;
  const int tid = threadIdx.x;

#pragma unroll
  for (int i = 0; i < 16; ++i) {
    int flat = i * 256 + tid;
    int lk = flat >> 6, ln = flat & 63;
    tile[lk][ln] = src[(size_t)(ks + lk) * 1024 + ns + ln];
  }
  __syncthreads();
#pragma unroll
  for (int i = 0; i < 16; ++i) {
    int flat = i * 256 + tid;
    int ln = flat >> 6, lk = flat & 63;
    bt[(size_t)(ntile + ln) * 2048 + ktile + lk] =
        __float2bfloat16(sgn * tile[lk][ln]);
  }
}

// ---------------------------------------------------------------------------
// Prologue 2: A -> bf16, combined [m][k] (k<1024: re, k>=1024: im).
// ---------------------------------------------------------------------------
__global__ __launch_bounds__(256) void convert_a(const float* __restrict__ re,
                                                 const float* __restrict__ im,
                                                 __hip_bfloat16* __restrict__ abf) {
  const int64_t total = (int64_t)32768 * 256;  // 8-elem chunks
  for (int64_t c = (int64_t)blockIdx.x * 256 + threadIdx.x; c < total;
       c += (int64_t)gridDim.x * 256) {
    int64_t m = c >> 8;
    int kc = (int)(c & 255) * 8;
    const float* src = (kc < 1024) ? re : im;
    const float* p = src + m * 1024 + (kc & 1023);
    f32x4 v0 = *(const f32x4*)p;
    f32x4 v1 = *(const f32x4*)(p + 4);
    bf16x8 h;
    h[0] = f2bf(v0[0]); h[1] = f2bf(v0[1]); h[2] = f2bf(v0[2]); h[3] = f2bf(v0[3]);
    h[4] = f2bf(v1[0]); h[5] = f2bf(v1[1]); h[6] = f2bf(v1[2]); h[7] = f2bf(v1[3]);
    *reinterpret_cast<bf16x8*>(reinterpret_cast<short*>(abf) + c * 8) = h;
  }
}

// ---------------------------------------------------------------------------
// Main GEMM: 256x256 tile, BK=64, 8 waves, 8-phase double-buffered schedule.
// ---------------------------------------------------------------------------
__global__ __launch_bounds__(512, 2)
void cgemm8(const __hip_bfloat16* __restrict__ abf,
            const __hip_bfloat16* __restrict__ bt, float* __restrict__ out) {
  __shared__ short Alds[2][256 * 64];  // [buf][row 0..255][k 0..63], swizzled
  __shared__ short Blds[2][256 * 64];

  const int tid = threadIdx.x;
  const int lane = tid & 63;
  const int w = tid >> 6;
  const int warm64 = (w >> 2) * 64;   // wave row offset within a 128-quadrant
  const int wn32 = (w & 3) * 32;      // wave col offset within a 128-quadrant
  const int fr_ = lane & 15;
  const int fq = lane >> 4;
  const int xmask = (fr_ & 7) << 4;   // T2 swizzle for fragment reads
  const int kx = fq * 16;             // fragment k-byte base

  // XCD-aware swizzle (nwg = 1024, %8==0), n-tile fastest.
  const int bid = blockIdx.x;
  const int swz = (bid & 7) * 128 + (bid >> 3);
  const int mt = swz >> 3;   // 0..127
  const int nt = swz & 7;    // 0..7

  const char* Asrc = (const char*)abf + (size_t)mt * 256 * 4096;
  const char* Bsrc = (const char*)bt + (size_t)nt * 256 * 4096;
  const char* Abase = (const char*)&Alds[0][0];
  const char* Bbase = (const char*)&Blds[0][0];

  f32x4 acc[4][4][2];  // [quadrant][mi][ni]
  const f32x4 zero = {0.f, 0.f, 0.f, 0.f};
#pragma unroll
  for (int q = 0; q < 4; ++q)
#pragma unroll
    for (int mi = 0; mi < 4; ++mi)
#pragma unroll
      for (int ni = 0; ni < 2; ++ni) acc[q][mi][ni] = zero;

  // Stage one half-tile (128 rows x 64 k, one operand): 2 x global_load_lds
  // w=16 per thread. LDS dest linear; T2 swizzle applied on global source.
  auto STAGE = [&](const char* src, int tt, int half, const char* ldsbase,
                   int buf) {
#pragma unroll
    for (int i = 0; i < 2; ++i) {
      int chunk = i * 512 + tid;   // 0..1023
      int row = chunk >> 3;        // 0..127 within half
      int kb = (chunk & 7) * 16;
      size_t so = (size_t)(half * 128 + row) * 4096 + tt * 128 +
                  (size_t)(kb ^ ((row & 7) << 4));
      __builtin_amdgcn_global_load_lds(
          (gas_ptr)(src + so),
          (las_ptr)((char*)ldsbase + buf * 32768 + half * 16384 + chunk * 16),
          16, 0, 0);
    }
  };

  // Prologue: tile0 all 4 halves + A0(1), B0(1); wait until tile0 landed.
  STAGE(Asrc, 0, 0, Abase, 0);
  STAGE(Bsrc, 0, 0, Bbase, 0);
  STAGE(Bsrc, 0, 1, Bbase, 0);
  STAGE(Asrc, 0, 1, Abase, 0);
  STAGE(Asrc, 1, 0, Abase, 1);
  STAGE(Bsrc, 1, 0, Bbase, 1);
  asm volatile("s_waitcnt vmcnt(4)" ::: "memory");
  __builtin_amdgcn_s_barrier();

#define PHASE(QM, QN, STAGE_STMT, WAIT_STMT)                                   \
  {                                                                            \
    bf16x8 af[4][2], bf_[2][2];                                                \
    _Pragma("unroll") for (int mi = 0; mi < 4; ++mi) {                         \
      int rowa = (QM) * 128 + warm64 + mi * 16 + fr_;                          \
      _Pragma("unroll") for (int ks = 0; ks < 2; ++ks)                         \
        af[mi][ks] = *(const bf16x8*)(Abase + cb * 32768 +                     \
                                      ((rowa * 128 + ks * 64 + kx) ^ xmask));  \
    }                                                                          \
    _Pragma("unroll") for (int ni = 0; ni < 2; ++ni) {                         \
      int rowb = (QN) * 128 + wn32 + ni * 16 + fr_;                            \
      _Pragma("unroll") for (int ks = 0; ks < 2; ++ks)                         \
        bf_[ni][ks] = *(const bf16x8*)(Bbase + cb * 32768 +                    \
                                       ((rowb * 128 + ks * 64 + kx) ^ xmask)); \
    }                                                                          \
    STAGE_STMT;                                                                \
    WAIT_STMT;                                                                 \
    __builtin_amdgcn_s_barrier();                                              \
    asm volatile("s_waitcnt lgkmcnt(0)" ::: "memory");                         \
    __builtin_amdgcn_sched_barrier(0);                                         \
    __builtin_amdgcn_s_setprio(1);                                             \
    _Pragma("unroll") for (int ks = 0; ks < 2; ++ks)                           \
      _Pragma("unroll") for (int mi = 0; mi < 4; ++mi)                         \
        _Pragma("unroll") for (int ni = 0; ni < 2; ++ni)                       \
          acc[(QM) * 2 + (QN)][mi][ni] =                                       \
              __builtin_amdgcn_mfma_f32_16x16x32_bf16(                         \
                  af[mi][ks], bf_[ni][ks], acc[(QM) * 2 + (QN)][mi][ni],       \
                  0, 0, 0);                                                    \
    __builtin_amdgcn_s_setprio(0);                                             \
    __builtin_amdgcn_s_barrier();                                              \
  }

#pragma unroll 2
  for (int t = 0; t < 32; ++t) {
    const int cb = t & 1;
    const int pb = cb ^ 1;

    PHASE(0, 0, { if (t < 31) STAGE(Bsrc, t + 1, 1, Bbase, pb); }, {})
    PHASE(0, 1, { if (t < 31) STAGE(Asrc, t + 1, 1, Abase, pb); }, {})
    PHASE(1, 0, { if (t < 30) STAGE(Asrc, t + 2, 0, Abase, cb); }, {})
    PHASE(1, 1, { if (t < 30) STAGE(Bsrc, t + 2, 0, Bbase, cb); },
          {
            if (t < 30) {
              asm volatile("s_waitcnt vmcnt(4)" ::: "memory");
            } else {
              asm volatile("s_waitcnt vmcnt(0)" ::: "memory");
            }
          })
  }
#undef PHASE

  // Epilogue: C/D layout col=lane&15, row=(lane>>4)*4+reg (m89-verified).
  const size_t half_elems = (size_t)32768 * 1024;
  float* ob = out + ((nt >= 4) ? half_elems : 0);
  const int ncol0 = (nt & 3) * 256;
  const size_t mrow0 = (size_t)mt * 256;
#pragma unroll
  for (int qm = 0; qm < 2; ++qm) {
#pragma unroll
    for (int qn = 0; qn < 2; ++qn) {
#pragma unroll
      for (int mi = 0; mi < 4; ++mi) {
#pragma unroll
        for (int ni = 0; ni < 2; ++ni) {
          int colg = ncol0 + qn * 128 + wn32 + ni * 16 + fr_;
          size_t rbase = mrow0 + qm * 128 + warm64 + mi * 16 + fq * 4;
#pragma unroll
          for (int j = 0; j < 4; ++j)
            ob[(rbase + j) * 1024 + colg] = acc[qm * 2 + qn][mi][ni][j];
        }
      }
    }
  }
}

// ---------------------------------------------------------------------------
// Fallback GEMM (round-1 path, proven): A fp32 reg-staged in-loop. Used only
// if ws_size can't hold the bf16 copy of A.
// ---------------------------------------------------------------------------
__global__ __launch_bounds__(256, 2)
void cgemm_f32a(const float* __restrict__ re, const float* __restrict__ im,
                const __hip_bfloat16* __restrict__ bt, float* __restrict__ out) {
  __shared__ short Alds[128 * 64];
  __shared__ short Blds[128 * 64];

  const int tid = threadIdx.x;
  const int lane = tid & 63;
  const int wid = tid >> 6;
  const int wr = wid >> 1, wc = wid & 1;
  const int fr_ = lane & 15;
  const int fq = lane >> 4;

  const int nwg = gridDim.x;
  const int bid = blockIdx.x;
  const int swz = (bid & 7) * (nwg >> 3) + (bid >> 3);
  const int mt = swz >> 4;
  const int nt = swz & 15;
  const size_t mbase = (size_t)mt * 128;
  const int nbase = nt * 128;

  f32x4 acc[4][4];
  const f32x4 zero = {0.f, 0.f, 0.f, 0.f};
#pragma unroll
  for (int i = 0; i < 4; ++i)
#pragma unroll
    for (int j = 0; j < 4; ++j) acc[i][j] = zero;

  const int arow_l = tid >> 3;
  const int akc = (tid & 7) * 8;
  const size_t aoff = (mbase + arow_l) * 1024 + akc;
  const char* btbase = (const char*)bt + (size_t)nbase * 4096;

  for (int kt = 0; kt < 32; ++kt) {
    const int k0 = kt * 64;
    const float* asrc = (k0 < 1024) ? re : im;
    const int kk = k0 & 1023;

    __syncthreads();

    const char* bsrc = btbase + (size_t)k0 * 2;
#pragma unroll
    for (int i = 0; i < 4; ++i) {
      int chunk = i * 256 + tid;
      int n = chunk >> 3;
      int kb = (chunk & 7) * 16;
      int srcoff = n * 4096 + (kb ^ ((n & 7) << 4));
      __builtin_amdgcn_global_load_lds((gas_ptr)(bsrc + srcoff),
                                       (las_ptr)((char*)Blds + chunk * 16),
                                       16, 0, 0);
    }

#pragma unroll
    for (int i = 0; i < 4; ++i) {
      int row = i * 32 + arow_l;
      const float* p = asrc + aoff + (size_t)i * 32 * 1024 + kk;
      f32x4 v0 = *(const f32x4*)p;
      f32x4 v1 = *(const f32x4*)(p + 4);
      bf16x8 h;
      h[0] = f2bf(v0[0]); h[1] = f2bf(v0[1]); h[2] = f2bf(v0[2]); h[3] = f2bf(v0[3]);
      h[4] = f2bf(v1[0]); h[5] = f2bf(v1[1]); h[6] = f2bf(v1[2]); h[7] = f2bf(v1[3]);
      int byte = (row * 128 + akc * 2) ^ ((row & 7) << 4);
      *reinterpret_cast<bf16x8*>(reinterpret_cast<char*>(Alds) + byte) = h;
    }

    __syncthreads();

#pragma unroll
    for (int ks = 0; ks < 2; ++ks) {
      bf16x8 af[4], bfr[4];
      const int koff = ks * 64 + fq * 16;
#pragma unroll
      for (int mi = 0; mi < 4; ++mi) {
        int row = wr * 64 + mi * 16 + fr_;
        int byte = (row * 128 + koff) ^ ((row & 7) << 4);
        af[mi] = *reinterpret_cast<const bf16x8*>(
            reinterpret_cast<const char*>(Alds) + byte);
      }
#pragma unroll
      for (int ni = 0; ni < 4; ++ni) {
        int row = wc * 64 + ni * 16 + fr_;
        int byte = (row * 128 + koff) ^ ((row & 7) << 4);
        bfr[ni] = *reinterpret_cast<const bf16x8*>(
            reinterpret_cast<const char*>(Blds) + byte);
      }
#pragma unroll
      for (int mi = 0; mi < 4; ++mi)
#pragma unroll
        for (int ni = 0; ni < 4; ++ni)
          acc[mi][ni] = __builtin_amdgcn_mfma_f32_16x16x32_bf16(
              af[mi], bfr[ni], acc[mi][ni], 0, 0, 0);
    }
  }

  const size_t half = (size_t)32768 * 1024;
  float* ob = out + ((nbase >= 1024) ? half : 0);
  const int ncol0 = nbase & 1023;
#pragma unroll
  for (int mi = 0; mi < 4; ++mi) {
#pragma unroll
    for (int ni = 0; ni < 4; ++ni) {
      int colg = ncol0 + wc * 64 + ni * 16 + fr_;
      size_t rbase = mbase + wr * 64 + mi * 16 + fq * 4;
#pragma unroll
      for (int j = 0; j < 4; ++j)
        ob[(rbase + j) * 1024 + colg] = acc[mi][ni][j];
    }
  }
}

extern "C" void kernel_launch(void* const* d_in, const int* in_sizes, int n_in,
                              void* d_out, int out_size, void* d_ws, size_t ws_size,
                              hipStream_t stream) {
  const float* re = (const float*)d_in[0];
  const float* im = (const float*)d_in[1];
  const float* fr = (const float*)d_in[2];
  const float* fi = (const float*)d_in[3];
  float* out = (float*)d_out;

  const size_t BT_BYTES = (size_t)2048 * 2048 * 2;           // 8 MB
  const size_t A_BYTES = (size_t)32768 * 2048 * 2;           // 134 MB
  __hip_bfloat16* bt = (__hip_bfloat16*)d_ws;

  build_bt<<<1024, 256, 0, stream>>>(fr, fi, bt);

  if (ws_size >= BT_BYTES + A_BYTES) {
    __hip_bfloat16* abf = (__hip_bfloat16*)((char*)d_ws + BT_BYTES);
    convert_a<<<2048, 256, 0, stream>>>(re, im, abf);
    cgemm8<<<1024, 512, 0, stream>>>(abf, bt, out);
  } else {
    cgemm_f32a<<<4096, 256, 0, stream>>>(re, im, bt, out);
  }
}